// Round 2
// baseline (363.908 us; speedup 1.0000x reference)
//
#include <hip/hip_runtime.h>
#include <hip/hip_bf16.h>
#include <stdint.h>
#include <stddef.h>

// Problem constants
#define BATCH   4096
#define INDIM   512
#define OUTDIM  512
#define NH      32
#define KKDIM   64                 // 2*NH k-values per input dim
#define INV2PI  0.15915494309189535f

// Occupancy-first tiling: 128x128 tile, 4 waves of 64x64, acc[4][4]=64 VGPR.
// B is read straight from L2 into registers (no LDS staging): LDS = 40 KB
// -> 4 blocks/CU co-resident (16 waves/CU vs round-1's 8). Round-1 showed
// LDS traffic/conflicts were NOT the limiter (25% fewer bytes, 98% fewer
// conflicts, identical 190us) -> latency-bound at 2 waves/SIMD; fix is TLP.
#define BM       128
#define BN       128
#define THREADS  256
#define KSPLIT   8
#define DIMS_PER_WG (INDIM / KSPLIT)     // 64 input dims per workgroup
#define CHUNK_COLS  256
#define CHUNK_ELEMS (CHUNK_COLS * KKDIM) // 16384 bf16 = 32 KB per (cb2, dim) chunk

// LDS layout (bytes): A dbuf + x dbuf only.
#define A_BYTES       (BM * 128)               // [128 row][64 kk] bf16, xor-swizzled (16 KB)
#define OFF_X         (2 * A_BYTES)            // 32768
#define X_CHUNK_BYTES (8 * BM * 4)             // 4096: [8 dims][128 rows] f32
#define SMEM_BYTES    (OFF_X + 2 * X_CHUNK_BYTES)  // 40960 -> 4 blocks/CU (160 KB/CU)

typedef short  bhalf8  __attribute__((ext_vector_type(8)));  // 8 bf16 (4 VGPRs)
typedef float  vfloat4 __attribute__((ext_vector_type(4)));

__device__ __forceinline__ unsigned pack_bf16(float a, float b) {
    union { __hip_bfloat162 h2; unsigned u; } cv;
    cv.h2 = __float22bfloat162_rn(float2{a, b});   // cos in low half (kk even), sin in high
    return cv.u;
}

// ---------------------------------------------------------------------------
// Prepass: fourier_coeffs fp32 [512,32,2,512] -> bf16 chunks in ws, LINEAR
// [col][kk] layout in 16B units (no swizzle needed: main kernel reads B from
// global/L2 into registers, not through LDS). Both global sides coalesced
// via LDS transpose.
// ---------------------------------------------------------------------------
__global__ __launch_bounds__(256) void fkan_prepass(const float* __restrict__ coeffs,
                                                    unsigned short* __restrict__ Bt) {
    __shared__ float lds[64][260];   // pad 260: conflict-free f32x4 writes + scalar reads
    const int t  = threadIdx.x;
    const int cb = blockIdx.x & 1;
    const int i  = blockIdx.x >> 1;
    const float* __restrict__ src = coeffs + (size_t)i * (KKDIM * OUTDIM) + cb * CHUNK_COLS;
    unsigned short* __restrict__ chunk = Bt + (size_t)(cb * INDIM + i) * CHUNK_ELEMS;
#pragma unroll
    for (int rd = 0; rd < 16; ++rd) {
        const int r  = rd * 4 + (t >> 6);       // each wave loads one kk-row, coalesced
        const int c4 = (t & 63) * 4;
        const float4 v = *(const float4*)(src + (size_t)r * OUTDIM + c4);
        *(float4*)&lds[r][c4] = v;
    }
    __syncthreads();
#pragma unroll
    for (int s = 0; s < 8; ++s) {
        const int unit = t + s * 256;          // 2048 16B-units per chunk
        const int col  = unit >> 3;
        const int kb   = (unit & 7) * 8;       // linear: unit u holds kk = 8u..8u+7 of col
        uint4 o;
        o.x = pack_bf16(lds[kb + 0][col], lds[kb + 1][col]);
        o.y = pack_bf16(lds[kb + 2][col], lds[kb + 3][col]);
        o.z = pack_bf16(lds[kb + 4][col], lds[kb + 5][col]);
        o.w = pack_bf16(lds[kb + 6][col], lds[kb + 7][col]);
        ((uint4*)chunk)[unit] = o;             // lane-contiguous coalesced store
    }
}

// out[b,o] = bias[o]
__global__ __launch_bounds__(256) void fkan_bias_init(const float* __restrict__ bias,
                                                      float* __restrict__ out) {
    const int idx = blockIdx.x * 256 + threadIdx.x;       // 524288 float4s
    ((float4*)out)[idx] = ((const float4*)bias)[idx & 127];
}

// ---------------------------------------------------------------------------
// Main fused kernel helpers
// ---------------------------------------------------------------------------
__device__ __forceinline__ void stage_x(const float* __restrict__ x, char* smem,
                                        int rowbase, int dimbase, int cn, int t) {
    const int r  = t >> 1;                     // 128 rows, 2 threads/row
    const int d0 = (t & 1) * 4;
    const float4 xv = *(const float4*)(x + (size_t)(rowbase + r) * INDIM + dimbase + cn * 8 + d0);
    float* xr = (float*)(smem + OFF_X + (cn & 1) * X_CHUNK_BYTES);  // [8][128] f32
    xr[(d0 + 0) * BM + r] = xv.x * INV2PI;     // revolutions; banks = r%32 -> 2-way (free)
    xr[(d0 + 1) * BM + r] = xv.y * INV2PI;
    xr[(d0 + 2) * BM + r] = xv.z * INV2PI;
    xr[(d0 + 3) * BM + r] = xv.w * INV2PI;
}

// cos/sin(k*x) for 16 harmonics via complex recurrence, packed bf16 pairs into
// A_lds[row][kk] (kk = 2*(k-1)+{0:cos,1:sin}), 16B-unit xor swizzle
// phys = unit ^ (row&7): writes and the MFMA av reads are both bank-uniform.
__device__ __forceinline__ void do_trig(char* smem, int dim_local, int parity, int trow, int tq) {
    const float rv = ((const float*)(smem + OFF_X + ((dim_local >> 3) & 1) * X_CHUNK_BYTES))
                     [(dim_local & 7) * BM + trow];
    const float cd = __builtin_amdgcn_cosf(rv);   // step e^{i*x} (revolution domain)
    const float sd = __builtin_amdgcn_sinf(rv);
    const float a0 = (float)(tq * 16 + 1) * rv;   // base harmonic k0 = tq*16+1
    float c = __builtin_amdgcn_cosf(a0);
    float s = __builtin_amdgcn_sinf(a0);
    unsigned pk[16];
    pk[0] = pack_bf16(c, s);
#pragma unroll
    for (int j = 1; j < 16; ++j) {
        const float nc = c * cd - s * sd;
        const float ns = s * cd + c * sd;
        c = nc; s = ns;
        pk[j] = pack_bf16(c, s);
    }
    uint4* abase = (uint4*)(smem + parity * A_BYTES + trow * 128);
    const int sw = trow & 7;
    uint4 w0; w0.x = pk[0];  w0.y = pk[1];  w0.z = pk[2];  w0.w = pk[3];
    uint4 w1; w1.x = pk[4];  w1.y = pk[5];  w1.z = pk[6];  w1.w = pk[7];
    uint4 w2; w2.x = pk[8];  w2.y = pk[9];  w2.z = pk[10]; w2.w = pk[11];
    uint4 w3; w3.x = pk[12]; w3.y = pk[13]; w3.z = pk[14]; w3.w = pk[15];
    abase[(tq * 4 + 0) ^ sw] = w0;
    abase[(tq * 4 + 1) ^ sw] = w1;
    abase[(tq * 4 + 2) ^ sw] = w2;
    abase[(tq * 4 + 3) ^ sw] = w3;
}

// ---------------------------------------------------------------------------
// Main kernel: grid 1024 (= 32 rowblocks x 4 colblocks x 8 ksplits), 256 thr.
// grp = blockIdx&31 -> (colblock, ksplit); members stride 32 so all 32 members
// of a group land on XCD grp%8; 4 groups/XCD x 1MB B working set = 4MB = L2.
// B fragments are loaded from global (L2-hit) into registers; only A (trig)
// and x go through LDS -> 40KB -> 4 blocks/CU for cross-block latency hiding.
// ---------------------------------------------------------------------------
__global__ __launch_bounds__(THREADS, 4) void fkan_main(const float* __restrict__ x,
                                                        const unsigned short* __restrict__ Bt,
                                                        float* __restrict__ out) {
    __shared__ char smem[SMEM_BYTES];
    const int t      = threadIdx.x;
    const int grp    = blockIdx.x & 31;
    const int member = blockIdx.x >> 5;
    const int cb4     = grp & 3;          // col block (128 cols)
    const int kq      = grp >> 2;         // ksplit
    const int cb2     = cb4 >> 1;         // prepass chunk half
    const int rowbase = member * BM;
    const int colbase = cb4 * BN;
    const int dimbase = kq * DIMS_PER_WG;

    const int lane = t & 63;
    const int w    = t >> 6;
    const int wr   = w >> 1;       // wave grid 2x2; wave tile 64x64
    const int wc   = w & 1;
    const int fr   = lane & 15;    // row/col within 16x16 tile
    const int fq   = lane >> 4;    // quad -> k-chunk of 8
    const int fx   = lane & 7;     // xor swizzle key for A (== row&7, tiles 16-aligned)

    const int trow = t >> 1;       // trig: 2 threads per row, 16 harmonics each
    const int tq   = t & 1;

    // Per-lane byte offset of this lane's B fragment base within a (cb2,dim) chunk.
    // bv[ks][ct] lives at + ct*16*128 + (ks*4+fq)*16.
    const int boff = ((cb4 & 1) * 128 + wc * 64 + fr) * 128 + fq * 16;
    const char* __restrict__ Bbase =
        (const char*)(Bt + (size_t)(cb2 * INDIM + dimbase) * CHUNK_ELEMS) + boff;

    vfloat4 acc[4][4];
#pragma unroll
    for (int a = 0; a < 4; ++a)
#pragma unroll
        for (int b = 0; b < 4; ++b) acc[a][b] = (vfloat4)0.0f;

    // Prologue: x chunk 0, then A for dim 0 into buffer 0.
    stage_x(x, smem, rowbase, dimbase, 0, t);
    __syncthreads();
    do_trig(smem, 0, 0, trow, tq);
    __syncthreads();

    for (int it = 0; it < DIMS_PER_WG; ++it) {
        const int p    = it & 1;
        const int inxt = it + 1;
        const char* Bc = Bbase + (size_t)it * (CHUNK_ELEMS * 2);

        // Issue ks=0 B loads first (L2 latency hides under trig + av reads).
        bhalf8 bv0[4];
#pragma unroll
        for (int ct = 0; ct < 4; ++ct)
            bv0[ct] = *(const bhalf8*)(Bc + ct * (16 * 128));

        if (inxt < DIMS_PER_WG) {
            if ((it & 7) == 0) {
                const int cn = (it >> 3) + 1;                     // stage x one chunk ahead
                if (cn < 8) stage_x(x, smem, rowbase, dimbase, cn, t);
            }
            do_trig(smem, inxt, inxt & 1, trow, tq);              // VALU, overlaps B loads
        }

        const char* Ab = smem + p * A_BYTES;
        __builtin_amdgcn_s_setprio(1);
        {   // ks = 0
            bhalf8 av[4];
#pragma unroll
            for (int rt = 0; rt < 4; ++rt)
                av[rt] = *(const bhalf8*)(Ab + (wr * 64 + rt * 16 + fr) * 128
                                             + ((fq ^ fx) * 16));
#pragma unroll
            for (int rt = 0; rt < 4; ++rt)
#pragma unroll
                for (int ct = 0; ct < 4; ++ct)
                    acc[rt][ct] = __builtin_amdgcn_mfma_f32_16x16x32_bf16(
                        av[rt], bv0[ct], acc[rt][ct], 0, 0, 0);
        }
        {   // ks = 1
            bhalf8 bv1[4];
#pragma unroll
            for (int ct = 0; ct < 4; ++ct)
                bv1[ct] = *(const bhalf8*)(Bc + ct * (16 * 128) + 4 * 16);
            bhalf8 av[4];
#pragma unroll
            for (int rt = 0; rt < 4; ++rt)
                av[rt] = *(const bhalf8*)(Ab + (wr * 64 + rt * 16 + fr) * 128
                                             + (((4 + fq) ^ fx) * 16));
#pragma unroll
            for (int rt = 0; rt < 4; ++rt)
#pragma unroll
                for (int ct = 0; ct < 4; ++ct)
                    acc[rt][ct] = __builtin_amdgcn_mfma_f32_16x16x32_bf16(
                        av[rt], bv1[ct], acc[rt][ct], 0, 0, 0);
        }
        __builtin_amdgcn_s_setprio(0);
        __syncthreads();
    }

    // Epilogue: C/D layout col=lane&15, row=quad*4+reg (m89). KSPLIT partials via atomics.
#pragma unroll
    for (int rt = 0; rt < 4; ++rt) {
#pragma unroll
        for (int ct = 0; ct < 4; ++ct) {
            const int col  = colbase + wc * 64 + ct * 16 + fr;
            const int row0 = rowbase + wr * 64 + rt * 16 + fq * 4;
#pragma unroll
            for (int r = 0; r < 4; ++r)
                atomicAdd(out + (size_t)(row0 + r) * OUTDIM + col, acc[rt][ct][r]);
        }
    }
}

// ---------------------------------------------------------------------------
// Fallback (only if ws too small for the 32MB bf16 B): slow but correct fp32.
// ---------------------------------------------------------------------------
__global__ __launch_bounds__(256) void fkan_naive(const float* __restrict__ x,
                                                  const float* __restrict__ coeffs,
                                                  const float* __restrict__ bias,
                                                  float* __restrict__ out) {
    const int b = blockIdx.x >> 1;
    const int o = ((blockIdx.x & 1) << 8) + threadIdx.x;
    float acc = bias[o];
    const float* xrow = x + (size_t)b * INDIM;
    for (int i = 0; i < INDIM; ++i) {
        const float rv = xrow[i] * INV2PI;
        const float cd = __builtin_amdgcn_cosf(rv);
        const float sd = __builtin_amdgcn_sinf(rv);
        float c = cd, s = sd;
        const float* cp = coeffs + (size_t)i * (KKDIM * OUTDIM) + o;
#pragma unroll 4
        for (int g = 0; g < NH; ++g) {
            acc += c * cp[g * 2 * OUTDIM] + s * cp[(g * 2 + 1) * OUTDIM];
            const float nc = c * cd - s * sd;
            const float ns = s * cd + c * sd;
            c = nc; s = ns;
        }
    }
    out[(size_t)b * OUTDIM + o] = acc;
}

extern "C" void kernel_launch(void* const* d_in, const int* in_sizes, int n_in,
                              void* d_out, int out_size, void* d_ws, size_t ws_size,
                              hipStream_t stream) {
    (void)in_sizes; (void)n_in; (void)out_size;
    const float* x      = (const float*)d_in[0];
    const float* coeffs = (const float*)d_in[1];
    const float* bias   = (const float*)d_in[2];
    float* out          = (float*)d_out;

    const size_t bt_bytes = (size_t)2 * INDIM * CHUNK_ELEMS * sizeof(unsigned short); // 32 MiB
    if (ws_size >= bt_bytes) {
        unsigned short* Bt = (unsigned short*)d_ws;
        fkan_prepass<<<2 * INDIM, 256, 0, stream>>>(coeffs, Bt);          // 1024 blocks
        fkan_bias_init<<<(BATCH * OUTDIM) / (4 * 256), 256, 0, stream>>>(bias, out);
        fkan_main<<<(BATCH / BM) * (OUTDIM / BN) * KSPLIT, THREADS, 0, stream>>>(x, Bt, out);
    } else {
        fkan_naive<<<BATCH * 2, 256, 0, stream>>>(x, coeffs, bias, out);
    }
}

// Round 3
// 343.766 us; speedup vs baseline: 1.0586x; 1.0586x over previous
//
#include <hip/hip_runtime.h>
#include <hip/hip_bf16.h>
#include <stdint.h>
#include <stddef.h>

// Problem constants
#define BATCH   4096
#define INDIM   512
#define OUTDIM  512
#define NH      32
#define KKDIM   64                 // 2*NH k-values per input dim
#define INV2PI  0.15915494309189535f

// Register-trig design: 128x128 tile, 4 waves of 64x64, acc[4][4] in AGPRs.
// A (trig) is computed per-lane directly into MFMA fragments -- never touches
// LDS. B keeps the proven global_load_lds dbuf path (round-2 showed B-from-
// global-to-reg exposes L2 latency: 190->296us). LDS = 40KB -> 4 blocks/CU.
#define BM       128
#define BN       128
#define THREADS  256
#define KSPLIT   8
#define DIMS_PER_WG (INDIM / KSPLIT)     // 64 input dims per workgroup
#define CHUNK_COLS  256
#define CHUNK_ELEMS (CHUNK_COLS * KKDIM) // 16384 bf16 = 32 KB per (cb2, dim) chunk

// LDS layout (bytes): B dbuf (16KB half-chunks) + x dbuf only. A: registers.
#define B_BYTES       16384                    // [128 col][64 kk] bf16, xor-swizzled
#define OFF_X         (2 * B_BYTES)            // 32768
#define X_CHUNK_BYTES (8 * BM * 4)             // 4096: [8 dims][128 rows] f32
#define SMEM_BYTES    (OFF_X + 2 * X_CHUNK_BYTES)  // 40960 -> 4 blocks/CU

typedef short  bhalf8  __attribute__((ext_vector_type(8)));  // 8 bf16 (4 VGPRs)
typedef float  vfloat4 __attribute__((ext_vector_type(4)));

union AFrag { uint4 u; bhalf8 h; };

__device__ __forceinline__ unsigned pack_bf16(float a, float b) {
    union { __hip_bfloat162 h2; unsigned u; } cv;
    cv.h2 = __float22bfloat162_rn(float2{a, b});   // cos in low half (kk even), sin in high
    return cv.u;
}

__device__ __forceinline__ void async_copy16(const void* gsrc, void* ldst) {
    __builtin_amdgcn_global_load_lds(
        (const __attribute__((address_space(1))) void*)(uintptr_t)gsrc,
        (__attribute__((address_space(3))) void*)(uint32_t)(uintptr_t)ldst,
        16, 0, 0);
}

// ---------------------------------------------------------------------------
// Prepass (identical to round-1 proven version): fourier_coeffs fp32
// [512,32,2,512] -> bf16 chunks [256 col][64 kk] with 16B-unit swizzle
// pc = (kk>>3) ^ (col&7) baked in. Main kernel stages 16KB col-halves.
// ---------------------------------------------------------------------------
__global__ __launch_bounds__(256) void fkan_prepass(const float* __restrict__ coeffs,
                                                    unsigned short* __restrict__ Bt) {
    __shared__ float lds[64][260];   // pad 260: conflict-free f32x4 writes + scalar reads
    const int t  = threadIdx.x;
    const int cb = blockIdx.x & 1;
    const int i  = blockIdx.x >> 1;
    const float* __restrict__ src = coeffs + (size_t)i * (KKDIM * OUTDIM) + cb * CHUNK_COLS;
    unsigned short* __restrict__ chunk = Bt + (size_t)(cb * INDIM + i) * CHUNK_ELEMS;
#pragma unroll
    for (int rd = 0; rd < 16; ++rd) {
        const int r  = rd * 4 + (t >> 6);       // each wave loads one kk-row, coalesced
        const int c4 = (t & 63) * 4;
        const float4 v = *(const float4*)(src + (size_t)r * OUTDIM + c4);
        *(float4*)&lds[r][c4] = v;
    }
    __syncthreads();
#pragma unroll
    for (int s = 0; s < 8; ++s) {
        const int unit = t + s * 256;          // 2048 16B-units per chunk
        const int col  = unit >> 3;
        const int pc   = unit & 7;             // physical 16B slot in this col's row
        const int kb   = (pc ^ (col & 7)) * 8; // logical kk base held in this slot
        uint4 o;
        o.x = pack_bf16(lds[kb + 0][col], lds[kb + 1][col]);
        o.y = pack_bf16(lds[kb + 2][col], lds[kb + 3][col]);
        o.z = pack_bf16(lds[kb + 4][col], lds[kb + 5][col]);
        o.w = pack_bf16(lds[kb + 6][col], lds[kb + 7][col]);
        ((uint4*)chunk)[unit] = o;             // lane-contiguous coalesced store
    }
}

// out[b,o] = bias[o]
__global__ __launch_bounds__(256) void fkan_bias_init(const float* __restrict__ bias,
                                                      float* __restrict__ out) {
    const int idx = blockIdx.x * 256 + threadIdx.x;       // 524288 float4s
    ((float4*)out)[idx] = ((const float4*)bias)[idx & 127];
}

// ---------------------------------------------------------------------------
// Main fused kernel helpers
// ---------------------------------------------------------------------------
__device__ __forceinline__ void stage_B(const char* __restrict__ chunk_half, char* smem,
                                        int parity, int t) {
    char* bdst = smem + parity * B_BYTES;
#pragma unroll
    for (int s = 0; s < 4; ++s) {
        const int unit = t + s * 256;          // 1024 16B-units per 16KB half-chunk
        async_copy16(chunk_half + unit * 16, bdst + unit * 16);  // linear DMA dest
    }
}

__device__ __forceinline__ void stage_x(const float* __restrict__ x, char* smem,
                                        int rowbase, int dimbase, int cn, int t) {
    const int r  = t >> 1;                     // 128 rows, 2 threads/row
    const int d0 = (t & 1) * 4;
    const float4 xv = *(const float4*)(x + (size_t)(rowbase + r) * INDIM + dimbase + cn * 8 + d0);
    float* xr = (float*)(smem + OFF_X + (cn & 1) * X_CHUNK_BYTES);  // [8][128] f32
    xr[(d0 + 0) * BM + r] = xv.x * INV2PI;     // revolutions; banks = r%32 -> 2-way (free)
    xr[(d0 + 1) * BM + r] = xv.y * INV2PI;
    xr[(d0 + 2) * BM + r] = xv.z * INV2PI;
    xr[(d0 + 3) * BM + r] = xv.w * INV2PI;
}

// ---------------------------------------------------------------------------
// Main kernel: grid 1024 (= 32 rowblocks x 4 colblocks x 8 ksplits), 256 thr.
// grp = blockIdx&31 -> (colblock, ksplit); members stride 32 so all 32 members
// of a group land on XCD grp%8; 4 groups/XCD x 1MB B working set = 4MB = L2.
// Per iter: issue B DMA for dim+1, compute trig fragments in registers
// (per lane: its own 4 rows x 8 harmonics, word-mapped exactly as the old
// LDS A-tile), 8 ds_read_b128 for bv, 32 MFMA, one barrier (B dbuf only).
// ---------------------------------------------------------------------------
__global__ __launch_bounds__(THREADS, 4) void fkan_main(const float* __restrict__ x,
                                                        const unsigned short* __restrict__ Bt,
                                                        float* __restrict__ out) {
    __shared__ char smem[SMEM_BYTES];
    const int t      = threadIdx.x;
    const int grp    = blockIdx.x & 31;
    const int member = blockIdx.x >> 5;
    const int cb4     = grp & 3;          // col block (128 cols)
    const int kq      = grp >> 2;         // ksplit
    const int cb2     = cb4 >> 1;         // prepass chunk (256-col) index
    const int rowbase = member * BM;
    const int colbase = cb4 * BN;
    const int dimbase = kq * DIMS_PER_WG;

    const int lane = t & 63;
    const int w    = t >> 6;
    const int wr   = w >> 1;       // wave grid 2x2; wave tile 64x64
    const int wc   = w & 1;
    const int fr   = lane & 15;    // row/col within 16x16 tile
    const int fq   = lane >> 4;    // quad -> k-chunk of 8 kk (4 harmonics)
    const int fx   = lane & 7;     // xor swizzle key for B (== col&7, tiles 16-aligned)

    const float k0f = (float)(fq * 4 + 1);    // ks=0 base harmonic
    const float k1f = (float)(fq * 4 + 17);   // ks=1 base harmonic

    // 16KB col-half of the (cb2, dim) 32KB chunk; dims stride 32KB.
    const char* __restrict__ chunkbase =
        (const char*)(Bt + (size_t)(cb2 * INDIM + dimbase) * CHUNK_ELEMS) + (cb4 & 1) * 16384;

    vfloat4 acc[4][4];
#pragma unroll
    for (int a = 0; a < 4; ++a)
#pragma unroll
        for (int b = 0; b < 4; ++b) acc[a][b] = (vfloat4)0.0f;

    // Prologue: x chunk 0 + B for dim 0; one full drain.
    stage_x(x, smem, rowbase, dimbase, 0, t);
    stage_B(chunkbase, smem, 0, t);
    __syncthreads();

#pragma unroll 2
    for (int it = 0; it < DIMS_PER_WG; ++it) {
        const int p    = it & 1;
        const int inxt = it + 1;
        if (inxt < DIMS_PER_WG)
            stage_B(chunkbase + (size_t)inxt * 32768, smem, inxt & 1, t);  // DMA overlaps below
        if ((it & 7) == 0) {
            const int cn = (it >> 3) + 1;                     // stage x one chunk ahead
            if (cn < 8) stage_x(x, smem, rowbase, dimbase, cn, t);
        }

        // Trig -> register A fragments. Word j of av0[rt] = pack(cos((k0f+j)x),
        // sin((k0f+j)x)) for row wr*64+rt*16+fr -- bit-identical to the old
        // LDS A-tile slot (ks*4+fq). 6 transcendentals + 6 rotations per row.
        const float* xr = (const float*)(smem + OFF_X + ((it >> 3) & 1) * X_CHUNK_BYTES)
                          + (it & 7) * BM;
        bhalf8 av0[4], av1[4];
#pragma unroll
        for (int rt = 0; rt < 4; ++rt) {
            const float rv = xr[wr * 64 + rt * 16 + fr];
            const float cd = __builtin_amdgcn_cosf(rv);   // step e^{ix} (revolutions)
            const float sd = __builtin_amdgcn_sinf(rv);
            AFrag A;
            float c = __builtin_amdgcn_cosf(k0f * rv);
            float s = __builtin_amdgcn_sinf(k0f * rv);
            A.u.x = pack_bf16(c, s);
            { const float nc = c*cd - s*sd, ns = s*cd + c*sd; c = nc; s = ns; }
            A.u.y = pack_bf16(c, s);
            { const float nc = c*cd - s*sd, ns = s*cd + c*sd; c = nc; s = ns; }
            A.u.z = pack_bf16(c, s);
            { const float nc = c*cd - s*sd, ns = s*cd + c*sd; c = nc; s = ns; }
            A.u.w = pack_bf16(c, s);
            av0[rt] = A.h;
            c = __builtin_amdgcn_cosf(k1f * rv);
            s = __builtin_amdgcn_sinf(k1f * rv);
            A.u.x = pack_bf16(c, s);
            { const float nc = c*cd - s*sd, ns = s*cd + c*sd; c = nc; s = ns; }
            A.u.y = pack_bf16(c, s);
            { const float nc = c*cd - s*sd, ns = s*cd + c*sd; c = nc; s = ns; }
            A.u.z = pack_bf16(c, s);
            { const float nc = c*cd - s*sd, ns = s*cd + c*sd; c = nc; s = ns; }
            A.u.w = pack_bf16(c, s);
            av1[rt] = A.h;
        }

        // MFMA phase: bv transient (8 VGPR live), av resident (32).
        const char* Bb = smem + p * B_BYTES;
        __builtin_amdgcn_s_setprio(1);
#pragma unroll
        for (int ct = 0; ct < 4; ++ct) {
            const int cbyte = (wc * 64 + ct * 16 + fr) * 128;
            const bhalf8 b0 = *(const bhalf8*)(Bb + cbyte + ((fq ^ fx) * 16));
#pragma unroll
            for (int rt = 0; rt < 4; ++rt)
                acc[rt][ct] = __builtin_amdgcn_mfma_f32_16x16x32_bf16(
                    av0[rt], b0, acc[rt][ct], 0, 0, 0);
            const bhalf8 b1 = *(const bhalf8*)(Bb + cbyte + (((4 + fq) ^ fx) * 16));
#pragma unroll
            for (int rt = 0; rt < 4; ++rt)
                acc[rt][ct] = __builtin_amdgcn_mfma_f32_16x16x32_bf16(
                    av1[rt], b1, acc[rt][ct], 0, 0, 0);
        }
        __builtin_amdgcn_s_setprio(0);
        __syncthreads();    // B[1-p] DMA drained (had full trig+MFMA to fly)
    }

    // Epilogue: C/D layout col=lane&15, row=quad*4+reg (m89). KSPLIT partials via atomics.
#pragma unroll
    for (int rt = 0; rt < 4; ++rt) {
#pragma unroll
        for (int ct = 0; ct < 4; ++ct) {
            const int col  = colbase + wc * 64 + ct * 16 + fr;
            const int row0 = rowbase + wr * 64 + rt * 16 + fq * 4;
#pragma unroll
            for (int r = 0; r < 4; ++r)
                atomicAdd(out + (size_t)(row0 + r) * OUTDIM + col, acc[rt][ct][r]);
        }
    }
}

// ---------------------------------------------------------------------------
// Fallback (only if ws too small for the 32MB bf16 B): slow but correct fp32.
// ---------------------------------------------------------------------------
__global__ __launch_bounds__(256) void fkan_naive(const float* __restrict__ x,
                                                  const float* __restrict__ coeffs,
                                                  const float* __restrict__ bias,
                                                  float* __restrict__ out) {
    const int b = blockIdx.x >> 1;
    const int o = ((blockIdx.x & 1) << 8) + threadIdx.x;
    float acc = bias[o];
    const float* xrow = x + (size_t)b * INDIM;
    for (int i = 0; i < INDIM; ++i) {
        const float rv = xrow[i] * INV2PI;
        const float cd = __builtin_amdgcn_cosf(rv);
        const float sd = __builtin_amdgcn_sinf(rv);
        float c = cd, s = sd;
        const float* cp = coeffs + (size_t)i * (KKDIM * OUTDIM) + o;
#pragma unroll 4
        for (int g = 0; g < NH; ++g) {
            acc += c * cp[g * 2 * OUTDIM] + s * cp[(g * 2 + 1) * OUTDIM];
            const float nc = c * cd - s * sd;
            const float ns = s * cd + c * sd;
            c = nc; s = ns;
        }
    }
    out[(size_t)b * OUTDIM + o] = acc;
}

extern "C" void kernel_launch(void* const* d_in, const int* in_sizes, int n_in,
                              void* d_out, int out_size, void* d_ws, size_t ws_size,
                              hipStream_t stream) {
    (void)in_sizes; (void)n_in; (void)out_size;
    const float* x      = (const float*)d_in[0];
    const float* coeffs = (const float*)d_in[1];
    const float* bias   = (const float*)d_in[2];
    float* out          = (float*)d_out;

    const size_t bt_bytes = (size_t)2 * INDIM * CHUNK_ELEMS * sizeof(unsigned short); // 32 MiB
    if (ws_size >= bt_bytes) {
        unsigned short* Bt = (unsigned short*)d_ws;
        fkan_prepass<<<2 * INDIM, 256, 0, stream>>>(coeffs, Bt);          // 1024 blocks
        fkan_bias_init<<<(BATCH * OUTDIM) / (4 * 256), 256, 0, stream>>>(bias, out);
        fkan_main<<<(BATCH / BM) * (OUTDIM / BN) * KSPLIT, THREADS, 0, stream>>>(x, Bt, out);
    } else {
        fkan_naive<<<BATCH * 2, 256, 0, stream>>>(x, coeffs, bias, out);
    }
}

// Round 4
// 279.331 us; speedup vs baseline: 1.3028x; 1.2307x over previous
//
#include <hip/hip_runtime.h>
#include <hip/hip_bf16.h>
#include <stdint.h>
#include <stddef.h>

// Problem constants
#define BATCH   4096
#define INDIM   512
#define OUTDIM  512
#define NH      32
#define KKDIM   64                 // 2*NH k-values per input dim
#define INV2PI  0.15915494309189535f

// Register-trig, zero-redundancy: 128x128 tile, 4 waves of 32x128 (4x1 grid),
// acc[2][8] in AGPRs. Round-3 post-mortem: 2x2 wave grid duplicated trig 2x
// across wc-paired waves -> VALU-bound (61% VALUBusy). 4x1 gives each wave
// disjoint rows: trig halves; B LDS reads go 2x (each wave reads full width)
// which the underutilized LDS pipe absorbs. B keeps the global_load_lds dbuf
// path (round-2 showed B-to-reg exposes L2 latency). LDS 40KB -> 4 blocks/CU.
#define BM       128
#define BN       128
#define THREADS  256
#define KSPLIT   8
#define DIMS_PER_WG (INDIM / KSPLIT)     // 64 input dims per workgroup
#define CHUNK_COLS  256
#define CHUNK_ELEMS (CHUNK_COLS * KKDIM) // 16384 bf16 = 32 KB per (cb2, dim) chunk

// LDS layout (bytes): B dbuf (16KB half-chunks) + x dbuf only. A: registers.
#define B_BYTES       16384                    // [128 col][64 kk] bf16, xor-swizzled
#define OFF_X         (2 * B_BYTES)            // 32768
#define X_CHUNK_BYTES (8 * BM * 4)             // 4096: [8 dims][128 rows] f32
#define SMEM_BYTES    (OFF_X + 2 * X_CHUNK_BYTES)  // 40960 -> 4 blocks/CU

typedef short  bhalf8  __attribute__((ext_vector_type(8)));  // 8 bf16 (4 VGPRs)
typedef float  vfloat4 __attribute__((ext_vector_type(4)));

union AFrag { uint4 u; bhalf8 h; };

__device__ __forceinline__ unsigned pack_bf16(float a, float b) {
    union { __hip_bfloat162 h2; unsigned u; } cv;
    cv.h2 = __float22bfloat162_rn(float2{a, b});   // cos in low half (kk even), sin in high
    return cv.u;
}

__device__ __forceinline__ void async_copy16(const void* gsrc, void* ldst) {
    __builtin_amdgcn_global_load_lds(
        (const __attribute__((address_space(1))) void*)(uintptr_t)gsrc,
        (__attribute__((address_space(3))) void*)(uint32_t)(uintptr_t)ldst,
        16, 0, 0);
}

// ---------------------------------------------------------------------------
// Prepass (proven since round 1): fourier_coeffs fp32 [512,32,2,512] -> bf16
// chunks [256 col][64 kk] with 16B-unit swizzle pc = (kk>>3) ^ (col&7) baked
// in. Main kernel stages 16KB col-halves. Both global sides coalesced.
// ---------------------------------------------------------------------------
__global__ __launch_bounds__(256) void fkan_prepass(const float* __restrict__ coeffs,
                                                    unsigned short* __restrict__ Bt) {
    __shared__ float lds[64][260];   // pad 260: conflict-free f32x4 writes + scalar reads
    const int t  = threadIdx.x;
    const int cb = blockIdx.x & 1;
    const int i  = blockIdx.x >> 1;
    const float* __restrict__ src = coeffs + (size_t)i * (KKDIM * OUTDIM) + cb * CHUNK_COLS;
    unsigned short* __restrict__ chunk = Bt + (size_t)(cb * INDIM + i) * CHUNK_ELEMS;
#pragma unroll
    for (int rd = 0; rd < 16; ++rd) {
        const int r  = rd * 4 + (t >> 6);       // each wave loads one kk-row, coalesced
        const int c4 = (t & 63) * 4;
        const float4 v = *(const float4*)(src + (size_t)r * OUTDIM + c4);
        *(float4*)&lds[r][c4] = v;
    }
    __syncthreads();
#pragma unroll
    for (int s = 0; s < 8; ++s) {
        const int unit = t + s * 256;          // 2048 16B-units per chunk
        const int col  = unit >> 3;
        const int pc   = unit & 7;             // physical 16B slot in this col's row
        const int kb   = (pc ^ (col & 7)) * 8; // logical kk base held in this slot
        uint4 o;
        o.x = pack_bf16(lds[kb + 0][col], lds[kb + 1][col]);
        o.y = pack_bf16(lds[kb + 2][col], lds[kb + 3][col]);
        o.z = pack_bf16(lds[kb + 4][col], lds[kb + 5][col]);
        o.w = pack_bf16(lds[kb + 6][col], lds[kb + 7][col]);
        ((uint4*)chunk)[unit] = o;             // lane-contiguous coalesced store
    }
}

// out[b,o] = bias[o]
__global__ __launch_bounds__(256) void fkan_bias_init(const float* __restrict__ bias,
                                                      float* __restrict__ out) {
    const int idx = blockIdx.x * 256 + threadIdx.x;       // 524288 float4s
    ((float4*)out)[idx] = ((const float4*)bias)[idx & 127];
}

// ---------------------------------------------------------------------------
// Main fused kernel helpers
// ---------------------------------------------------------------------------
__device__ __forceinline__ void stage_B(const char* __restrict__ chunk_half, char* smem,
                                        int parity, int t) {
    char* bdst = smem + parity * B_BYTES;
#pragma unroll
    for (int s = 0; s < 4; ++s) {
        const int unit = t + s * 256;          // 1024 16B-units per 16KB half-chunk
        async_copy16(chunk_half + unit * 16, bdst + unit * 16);  // linear DMA dest
    }
}

__device__ __forceinline__ void stage_x(const float* __restrict__ x, char* smem,
                                        int rowbase, int dimbase, int cn, int t) {
    const int r  = t >> 1;                     // 128 rows, 2 threads/row
    const int d0 = (t & 1) * 4;
    const float4 xv = *(const float4*)(x + (size_t)(rowbase + r) * INDIM + dimbase + cn * 8 + d0);
    float* xr = (float*)(smem + OFF_X + (cn & 1) * X_CHUNK_BYTES);  // [8][128] f32
    xr[(d0 + 0) * BM + r] = xv.x * INV2PI;     // revolutions; banks = r%32 -> 2-way (free)
    xr[(d0 + 1) * BM + r] = xv.y * INV2PI;
    xr[(d0 + 2) * BM + r] = xv.z * INV2PI;
    xr[(d0 + 3) * BM + r] = xv.w * INV2PI;
}

// ---------------------------------------------------------------------------
// Main kernel: grid 1024 (= 32 rowblocks x 4 colblocks x 8 ksplits), 256 thr.
// grp = blockIdx&31 = cb4*8 + kq -> XCD (= blockIdx%8) is kq: all 4 colblocks
// of one ksplit share an XCD, so its L2 working set is 64 dims x 32KB = 2MB of
// B + 1MB of x = 3MB <= 4MB with slack (round-3's (cb,kq) grouping sat at
// exactly 4MB -> member drift thrashed L2: FETCH 75MB).
// Per iter: issue next B DMA, per-lane register trig for this wave's OWN 32
// rows (no cross-wave redundancy), 16 ds_read_b128 bv, 32 MFMA, one barrier.
// ---------------------------------------------------------------------------
__global__ __launch_bounds__(THREADS, 4) void fkan_main(const float* __restrict__ x,
                                                        const unsigned short* __restrict__ Bt,
                                                        float* __restrict__ out) {
    __shared__ char smem[SMEM_BYTES];
    const int t      = threadIdx.x;
    const int grp    = blockIdx.x & 31;
    const int member = blockIdx.x >> 5;
    const int kq      = grp & 7;          // ksplit -> XCD
    const int cb4     = grp >> 3;         // col block (128 cols)
    const int cb2     = cb4 >> 1;         // prepass chunk (256-col) index
    const int rowbase = member * BM;
    const int colbase = cb4 * BN;
    const int dimbase = kq * DIMS_PER_WG;

    const int lane = t & 63;
    const int w    = t >> 6;       // wave grid 4x1; wave tile 32x128 (rows w*32..)
    const int fr   = lane & 15;    // row/col within 16x16 tile
    const int fq   = lane >> 4;    // quad -> k-chunk of 8 kk (4 harmonics)
    const int fx   = lane & 7;     // xor swizzle key for B (== col&7, tiles 16-aligned)

    const float k0f = (float)(fq * 4 + 1);    // ks=0 base harmonic
    const float k1f = (float)(fq * 4 + 17);   // ks=1 base harmonic

    // 16KB col-half of the (cb2, dim) 32KB chunk; dims stride 32KB.
    const char* __restrict__ chunkbase =
        (const char*)(Bt + (size_t)(cb2 * INDIM + dimbase) * CHUNK_ELEMS) + (cb4 & 1) * 16384;

    vfloat4 acc[2][8];
#pragma unroll
    for (int a = 0; a < 2; ++a)
#pragma unroll
        for (int b = 0; b < 8; ++b) acc[a][b] = (vfloat4)0.0f;

    // Prologue: x chunk 0 + B for dim 0; one full drain.
    stage_x(x, smem, rowbase, dimbase, 0, t);
    stage_B(chunkbase, smem, 0, t);
    __syncthreads();

#pragma unroll 2
    for (int it = 0; it < DIMS_PER_WG; ++it) {
        const int p    = it & 1;
        const int inxt = it + 1;
        if (inxt < DIMS_PER_WG)
            stage_B(chunkbase + (size_t)inxt * 32768, smem, inxt & 1, t);  // DMA overlaps below
        if ((it & 7) == 0) {
            const int cn = (it >> 3) + 1;                     // stage x one chunk ahead
            if (cn < 8) stage_x(x, smem, rowbase, dimbase, cn, t);
        }

        // Trig -> register A fragments for THIS wave's rows only (w*32 + rt*16
        // + fr, rt in {0,1}). Word j of av0[rt] = pack(cos((k0f+j)x),
        // sin((k0f+j)x)) -- slot-identical to the LDS A-tile of rounds 0/1.
        const float* xr = (const float*)(smem + OFF_X + ((it >> 3) & 1) * X_CHUNK_BYTES)
                          + (it & 7) * BM;
        bhalf8 av0[2], av1[2];
#pragma unroll
        for (int rt = 0; rt < 2; ++rt) {
            const float rv = xr[w * 32 + rt * 16 + fr];
            const float cd = __builtin_amdgcn_cosf(rv);   // step e^{ix} (revolutions)
            const float sd = __builtin_amdgcn_sinf(rv);
            AFrag A;
            float c = __builtin_amdgcn_cosf(k0f * rv);
            float s = __builtin_amdgcn_sinf(k0f * rv);
            A.u.x = pack_bf16(c, s);
            { const float nc = c*cd - s*sd, ns = s*cd + c*sd; c = nc; s = ns; }
            A.u.y = pack_bf16(c, s);
            { const float nc = c*cd - s*sd, ns = s*cd + c*sd; c = nc; s = ns; }
            A.u.z = pack_bf16(c, s);
            { const float nc = c*cd - s*sd, ns = s*cd + c*sd; c = nc; s = ns; }
            A.u.w = pack_bf16(c, s);
            av0[rt] = A.h;
            c = __builtin_amdgcn_cosf(k1f * rv);
            s = __builtin_amdgcn_sinf(k1f * rv);
            A.u.x = pack_bf16(c, s);
            { const float nc = c*cd - s*sd, ns = s*cd + c*sd; c = nc; s = ns; }
            A.u.y = pack_bf16(c, s);
            { const float nc = c*cd - s*sd, ns = s*cd + c*sd; c = nc; s = ns; }
            A.u.z = pack_bf16(c, s);
            { const float nc = c*cd - s*sd, ns = s*cd + c*sd; c = nc; s = ns; }
            A.u.w = pack_bf16(c, s);
            av1[rt] = A.h;
        }

        // MFMA phase: full-width B (8 col-tiles), bv transient, av resident.
        const char* Bb = smem + p * B_BYTES;
        __builtin_amdgcn_s_setprio(1);
#pragma unroll
        for (int ct = 0; ct < 8; ++ct) {
            const int cbyte = (ct * 16 + fr) * 128;
            const bhalf8 b0 = *(const bhalf8*)(Bb + cbyte + ((fq ^ fx) * 16));
            acc[0][ct] = __builtin_amdgcn_mfma_f32_16x16x32_bf16(av0[0], b0, acc[0][ct], 0, 0, 0);
            acc[1][ct] = __builtin_amdgcn_mfma_f32_16x16x32_bf16(av0[1], b0, acc[1][ct], 0, 0, 0);
            const bhalf8 b1 = *(const bhalf8*)(Bb + cbyte + (((4 + fq) ^ fx) * 16));
            acc[0][ct] = __builtin_amdgcn_mfma_f32_16x16x32_bf16(av1[0], b1, acc[0][ct], 0, 0, 0);
            acc[1][ct] = __builtin_amdgcn_mfma_f32_16x16x32_bf16(av1[1], b1, acc[1][ct], 0, 0, 0);
        }
        __builtin_amdgcn_s_setprio(0);
        __syncthreads();    // B[1-p] DMA drained (had full trig+MFMA to fly)
    }

    // Epilogue: C/D layout col=lane&15, row=quad*4+reg (m89). KSPLIT partials via atomics.
#pragma unroll
    for (int rt = 0; rt < 2; ++rt) {
#pragma unroll
        for (int ct = 0; ct < 8; ++ct) {
            const int col  = colbase + ct * 16 + fr;
            const int row0 = rowbase + w * 32 + rt * 16 + fq * 4;
#pragma unroll
            for (int r = 0; r < 4; ++r)
                atomicAdd(out + (size_t)(row0 + r) * OUTDIM + col, acc[rt][ct][r]);
        }
    }
}

// ---------------------------------------------------------------------------
// Fallback (only if ws too small for the 32MB bf16 B): slow but correct fp32.
// ---------------------------------------------------------------------------
__global__ __launch_bounds__(256) void fkan_naive(const float* __restrict__ x,
                                                  const float* __restrict__ coeffs,
                                                  const float* __restrict__ bias,
                                                  float* __restrict__ out) {
    const int b = blockIdx.x >> 1;
    const int o = ((blockIdx.x & 1) << 8) + threadIdx.x;
    float acc = bias[o];
    const float* xrow = x + (size_t)b * INDIM;
    for (int i = 0; i < INDIM; ++i) {
        const float rv = xrow[i] * INV2PI;
        const float cd = __builtin_amdgcn_cosf(rv);
        const float sd = __builtin_amdgcn_sinf(rv);
        float c = cd, s = sd;
        const float* cp = coeffs + (size_t)i * (KKDIM * OUTDIM) + o;
#pragma unroll 4
        for (int g = 0; g < NH; ++g) {
            acc += c * cp[g * 2 * OUTDIM] + s * cp[(g * 2 + 1) * OUTDIM];
            const float nc = c * cd - s * sd;
            const float ns = s * cd + c * sd;
            c = nc; s = ns;
        }
    }
    out[(size_t)b * OUTDIM + o] = acc;
}

extern "C" void kernel_launch(void* const* d_in, const int* in_sizes, int n_in,
                              void* d_out, int out_size, void* d_ws, size_t ws_size,
                              hipStream_t stream) {
    (void)in_sizes; (void)n_in; (void)out_size;
    const float* x      = (const float*)d_in[0];
    const float* coeffs = (const float*)d_in[1];
    const float* bias   = (const float*)d_in[2];
    float* out          = (float*)d_out;

    const size_t bt_bytes = (size_t)2 * INDIM * CHUNK_ELEMS * sizeof(unsigned short); // 32 MiB
    if (ws_size >= bt_bytes) {
        unsigned short* Bt = (unsigned short*)d_ws;
        fkan_prepass<<<2 * INDIM, 256, 0, stream>>>(coeffs, Bt);          // 1024 blocks
        fkan_bias_init<<<(BATCH * OUTDIM) / (4 * 256), 256, 0, stream>>>(bias, out);
        fkan_main<<<(BATCH / BM) * (OUTDIM / BN) * KSPLIT, THREADS, 0, stream>>>(x, Bt, out);
    } else {
        fkan_naive<<<BATCH * 2, 256, 0, stream>>>(x, coeffs, bias, out);
    }
}